// Round 4
// baseline (225091.602 us; speedup 1.0000x reference)
//
#include <hip/hip_runtime.h>
#include <math.h>

#define WORDN 1024
#define HIDN  2048
#define ENCN  512
#define NODEN 8192
#define NSTEP (NODEN - 1)

#define CHAIN_WGS 32
#define SENT32 0x7F7F7F7Fu   // byte-0x7F memset pattern = 3.39e38f, impossible for tanh output

// ---------------------------------------------------------------------------
// Persistent sequential-chain kernel: P[t+1] = tanh(W @ P[t] + addv_t)
// 32 WGs x 256 threads = 128 independent waves. Wave owns 8 rows; lane owns
// one (row, 128-col segment) pair; 128 weights/lane in VGPRs.
//
// Sync: ZERO fences, ZERO flags. P rows 1.. are pre-set to 0x7F7F7F7F
// (3.4e38). Producers write rows with relaxed agent-scope stores (sc1,
// write-through to MALL). Consumers poll their own 512 B segment with
// relaxed agent-scope 8 B loads (bypass L1/L2 -> always fresh) until no
// dword equals the sentinel, then compute FROM THOSE REGISTERS. Each P
// element transitions sentinel -> tanh-value exactly once, so observing a
// non-sentinel value IS the synchronization; no ordering needed.
// ---------------------------------------------------------------------------
__global__ __launch_bounds__(256, 1) void chain_kernel(
    const float* __restrict__ W, int ldw, int row_off,
    const float* __restrict__ addv, long addv_stride,
    float* __restrict__ P)
{
  const int g    = blockIdx.x;       // 0..31
  const int tid  = threadIdx.x;      // 0..255
  const int lane = tid & 63;
  const int wave = tid >> 6;
  const int rloc = (wave << 3) | (lane >> 3);  // row within WG 0..31
  const int row  = (g << 5) | rloc;            // 0..1023
  const int seg  = lane & 7;                   // 128-col segment

  // One-time: this lane's 128 weights into VGPRs (as 64 float2).
  float2 w[64];
  {
    const float* wr = W + (long)(row_off + row) * ldw + (seg << 7);
    #pragma unroll
    for (int i = 0; i < 64; ++i) w[i] = ((const float2*)wr)[i];
  }

  for (int t = 0; t < NSTEP; ++t) {
    // Additive term (plain load; U-stream / broadcast bias, L2-friendly).
    float av = addv[(long)t * addv_stride + row];

    // Acquire this lane's 512 B segment of P[t] into registers.
    unsigned long long d[64];
    const unsigned long long* src =
        (const unsigned long long*)(P + ((long)t << 10) + (seg << 7));
    if (t == 0) {
      // Seed row written by a previous dispatch -> coherent via dispatch
      // boundary; plain loads.
      #pragma unroll
      for (int i = 0; i < 64; ++i) d[i] = src[i];
    } else {
      while (true) {
        bool ok = true;
        #pragma unroll
        for (int i = 0; i < 64; ++i) {
          d[i] = __hip_atomic_load(src + i, __ATOMIC_RELAXED,
                                   __HIP_MEMORY_SCOPE_AGENT);
          unsigned lo = (unsigned)d[i];
          unsigned hi = (unsigned)(d[i] >> 32);
          ok = ok && (lo != SENT32) && (hi != SENT32);
        }
        if (__all(ok)) break;
        __builtin_amdgcn_s_sleep(1);
      }
    }

    // Dot product from registers (4 accumulators for FMA-latency ILP).
    float a0 = 0.f, a1 = 0.f, a2 = 0.f, a3 = 0.f;
    #pragma unroll
    for (int i = 0; i < 64; i += 2) {
      float2 p0 = make_float2(__uint_as_float((unsigned)d[i]),
                              __uint_as_float((unsigned)(d[i] >> 32)));
      float2 p1 = make_float2(__uint_as_float((unsigned)d[i + 1]),
                              __uint_as_float((unsigned)(d[i + 1] >> 32)));
      a0 = fmaf(w[i].x, p0.x, a0);
      a1 = fmaf(w[i].y, p0.y, a1);
      a2 = fmaf(w[i + 1].x, p1.x, a2);
      a3 = fmaf(w[i + 1].y, p1.y, a3);
    }
    float acc = (a0 + a1) + (a2 + a3);
    // Reduce across the 8 lanes sharing a row.
    acc += __shfl_xor(acc, 1);
    acc += __shfl_xor(acc, 2);
    acc += __shfl_xor(acc, 4);
    if (seg == 0) {
      float outv = tanhf(acc + av);
      // Relaxed agent store: write-through to MALL; no fence needed.
      __hip_atomic_store((unsigned int*)(P + ((long)(t + 1) << 10) + row),
                         __float_as_uint(outv),
                         __ATOMIC_RELAXED, __HIP_MEMORY_SCOPE_AGENT);
    }
  }
}

// ---------------------------------------------------------------------------
// Wave-per-row matvec: y[r] = tanh(W[row_off+r,:] . x + b[b_off+r])
// ---------------------------------------------------------------------------
__global__ void matvec_tanh(const float* __restrict__ W, int ldw, int row_off,
                            const float* __restrict__ x, int K,
                            const float* __restrict__ b, int b_off,
                            float* __restrict__ y, int M)
{
  int gw   = (int)((blockIdx.x * blockDim.x + threadIdx.x) >> 6);
  int lane = threadIdx.x & 63;
  if (gw >= M) return;
  const float* wr = W + (long)(row_off + gw) * ldw;
  float acc = 0.f;
  for (int k = lane << 2; k < K; k += 256) {
    float4 wv = *(const float4*)(wr + k);
    float4 xv = *(const float4*)(x + k);
    acc = fmaf(wv.x, xv.x, acc);
    acc = fmaf(wv.y, xv.y, acc);
    acc = fmaf(wv.z, xv.z, acc);
    acc = fmaf(wv.w, xv.w, acc);
  }
  #pragma unroll
  for (int off = 1; off < 64; off <<= 1) acc += __shfl_xor(acc, off);
  if (lane == 0) y[gw] = tanhf(acc + b[b_off + gw]);
}

// z = eps * exp(0.5*va) + mu   (512 elements)
__global__ void z_kernel(const float* __restrict__ eps, const float* __restrict__ mu,
                         const float* __restrict__ va, float* __restrict__ z)
{
  int i = blockIdx.x * blockDim.x + threadIdx.x;
  z[i] = eps[i] * expf(0.5f * va[i]) + mu[i];
}

// ---------------------------------------------------------------------------
// fp32 tiled GEMM: C[crow(m), n] = (tanh?)( sum_k A[a_row0+m, k]*B[b_row0+n, k] + bias[n] )
// crow(m) = rev ? (M - m) : m.   BM=BN=128, BK=8, 256 threads, 8x8 microtile.
// ---------------------------------------------------------------------------
#define GBM 128
#define GBN 128
#define GBK 8

__global__ __launch_bounds__(256, 2) void gemm_bt(
    const float* __restrict__ A, long lda, long a_row0,
    const float* __restrict__ B, long ldb, long b_row0,
    const float* __restrict__ bias, long bias_off,
    float* __restrict__ C, long ldc,
    int M, int N, int K, int rev, int do_tanh)
{
  __shared__ float As[GBK][GBM + 4];
  __shared__ float Bs[GBK][GBN + 4];

  const int tid = threadIdx.x;
  const int bm = blockIdx.x, bn = blockIdx.y;
  const int tx = tid & 15;    // n dir
  const int ty = tid >> 4;    // m dir
  const int lr = tid >> 1;          // 0..127 staging row
  const int lc = (tid & 1) << 2;    // 0 or 4 staging col

  float acc[8][8];
  #pragma unroll
  for (int i = 0; i < 8; ++i)
    #pragma unroll
    for (int j = 0; j < 8; ++j) acc[i][j] = 0.f;

  for (int k0 = 0; k0 < K; k0 += GBK) {
    int am = bm * GBM + lr;
    float4 avv = make_float4(0.f, 0.f, 0.f, 0.f);
    if (am < M) avv = *(const float4*)(A + (a_row0 + am) * lda + k0 + lc);
    int bnr = bn * GBN + lr;
    float4 bvv = *(const float4*)(B + (b_row0 + bnr) * ldb + k0 + lc);

    As[lc + 0][lr] = avv.x; As[lc + 1][lr] = avv.y;
    As[lc + 2][lr] = avv.z; As[lc + 3][lr] = avv.w;
    Bs[lc + 0][lr] = bvv.x; Bs[lc + 1][lr] = bvv.y;
    Bs[lc + 2][lr] = bvv.z; Bs[lc + 3][lr] = bvv.w;
    __syncthreads();

    #pragma unroll
    for (int k = 0; k < GBK; ++k) {
      float4 a0 = *(const float4*)&As[k][ty << 2];
      float4 a1 = *(const float4*)&As[k][64 + (ty << 2)];
      float4 b0 = *(const float4*)&Bs[k][tx << 2];
      float4 b1 = *(const float4*)&Bs[k][64 + (tx << 2)];
      float aa[8] = {a0.x, a0.y, a0.z, a0.w, a1.x, a1.y, a1.z, a1.w};
      float bb[8] = {b0.x, b0.y, b0.z, b0.w, b1.x, b1.y, b1.z, b1.w};
      #pragma unroll
      for (int i = 0; i < 8; ++i)
        #pragma unroll
        for (int j = 0; j < 8; ++j)
          acc[i][j] = fmaf(aa[i], bb[j], acc[i][j]);
    }
    __syncthreads();
  }

  // Epilogue
  #pragma unroll
  for (int hm = 0; hm < 2; ++hm) {
    #pragma unroll
    for (int i = 0; i < 4; ++i) {
      int m = bm * GBM + hm * 64 + (ty << 2) + i;
      if (m >= M) continue;
      long crow = rev ? (long)(M - m) : (long)m;
      #pragma unroll
      for (int hn = 0; hn < 2; ++hn) {
        int n0 = bn * GBN + hn * 64 + (tx << 2);
        float4 v;
        v.x = acc[hm * 4 + i][hn * 4 + 0] + bias[bias_off + n0 + 0];
        v.y = acc[hm * 4 + i][hn * 4 + 1] + bias[bias_off + n0 + 1];
        v.z = acc[hm * 4 + i][hn * 4 + 2] + bias[bias_off + n0 + 2];
        v.w = acc[hm * 4 + i][hn * 4 + 3] + bias[bias_off + n0 + 3];
        if (do_tanh) {
          v.x = tanhf(v.x); v.y = tanhf(v.y); v.z = tanhf(v.z); v.w = tanhf(v.w);
        }
        *(float4*)(C + crow * ldc + n0) = v;
      }
    }
  }
}

// ---------------------------------------------------------------------------
extern "C" void kernel_launch(void* const* d_in, const int* in_sizes, int n_in,
                              void* d_out, int out_size, void* d_ws, size_t ws_size,
                              hipStream_t stream)
{
  const float* sent    = (const float*)d_in[0];
  const float* eps     = (const float*)d_in[1];
  const float* WeC2P_w = (const float*)d_in[2];
  const float* WeC2P_b = (const float*)d_in[3];
  const float* WeP2H_w = (const float*)d_in[4];
  const float* WeP2H_b = (const float*)d_in[5];
  const float* WeH2M_w = (const float*)d_in[6];
  const float* WeH2M_b = (const float*)d_in[7];
  const float* WeH2D_w = (const float*)d_in[8];
  const float* WeH2D_b = (const float*)d_in[9];
  const float* WdE2H_w = (const float*)d_in[10];
  const float* WdE2H_b = (const float*)d_in[11];
  const float* WdH2P_w = (const float*)d_in[12];
  const float* WdH2P_b = (const float*)d_in[13];
  const float* WdP2C_w = (const float*)d_in[14];
  const float* WdP2C_b = (const float*)d_in[15];
  float* out = (float*)d_out;

  char* ws = (char*)d_ws;
  float* hid  = (float*)(ws + 16384);                          // 2048
  float* mu   = hid + HIDN;                                    // 512
  float* va   = mu + ENCN;                                     // 512
  float* z    = va + ENCN;                                     // 512
  float* hdec = z + ENCN;                                      // 2048
  float* P    = (float*)(ws + 65536);                          // 8192 x 1024 fp32 (32 MB)

  const size_t prow = (size_t)WORDN * sizeof(float);

  // Sentinel-fill P rows 1..8191 (0x7F bytes -> 0x7F7F7F7F dwords = 3.4e38).
  hipMemsetAsync(P + WORDN, 0x7F, (size_t)NSTEP * prow, stream);
  // P[0] = sent[0]  (encode seed)
  hipMemcpyAsync(P, sent, prow, hipMemcpyDeviceToDevice, stream);

  dim3 gg((NSTEP + GBM - 1) / GBM, WORDN / GBN);  // (64, 8)

  // U[t] = Wx @ sent[t+1] + b_enc   -> stored in d_out (scratch; overwritten later)
  gemm_bt<<<gg, 256, 0, stream>>>(sent, WORDN, 1,
                                  WeC2P_w + WORDN, 2 * WORDN, 0,
                                  WeC2P_b, 0,
                                  out, WORDN,
                                  NSTEP, WORDN, WORDN, 0, 0);

  // Encode chain: P[t+1] = tanh(Wp @ P[t] + U[t]),  t = 0..8190
  chain_kernel<<<CHAIN_WGS, 256, 0, stream>>>(WeC2P_w, 2 * WORDN, 0,
                                              out, WORDN, P);

  // hid = tanh(WeP2H @ P[8191] + b)
  matvec_tanh<<<(HIDN * 64) / 256, 256, 0, stream>>>(WeP2H_w, WORDN, 0,
                                                     P + (long)NSTEP * WORDN, WORDN,
                                                     WeP2H_b, 0, hid, HIDN);
  // mu, va
  matvec_tanh<<<(ENCN * 64) / 256, 256, 0, stream>>>(WeH2M_w, HIDN, 0, hid, HIDN,
                                                     WeH2M_b, 0, mu, ENCN);
  matvec_tanh<<<(ENCN * 64) / 256, 256, 0, stream>>>(WeH2D_w, HIDN, 0, hid, HIDN,
                                                     WeH2D_b, 0, va, ENCN);
  // z = eps * exp(0.5 va) + mu
  z_kernel<<<ENCN / 256, 256, 0, stream>>>(eps, mu, va, z);
  // hdec = tanh(WdE2H @ z + b)
  matvec_tanh<<<(HIDN * 64) / 256, 256, 0, stream>>>(WdE2H_w, ENCN, 0, z, ENCN,
                                                     WdE2H_b, 0, hdec, HIDN);

  // Re-sentinel P rows 1..8191 for the decode chain (stream-ordered after
  // all encode readers of P).
  hipMemsetAsync(P + WORDN, 0x7F, (size_t)NSTEP * prow, stream);

  // parent_d = tanh(WdH2P @ hdec + b)  -> P[0]  (decode seed)
  matvec_tanh<<<(WORDN * 64) / 256, 256, 0, stream>>>(WdH2P_w, HIDN, 0, hdec, HIDN,
                                                      WdH2P_b, 0, P, WORDN);

  // Decode chain: P[t+1] = tanh(Wbot @ P[t] + b_bot), t = 0..8190
  chain_kernel<<<CHAIN_WGS, 256, 0, stream>>>(WdP2C_w, WORDN, WORDN,
                                              WdP2C_b + WORDN, 0, P);

  // out[8191 - i] = tanh(Wtop @ P[i] + b_top), i = 0..8190
  gemm_bt<<<gg, 256, 0, stream>>>(P, WORDN, 0,
                                  WdP2C_w, WORDN, 0,
                                  WdP2C_b, 0,
                                  out, WORDN,
                                  NSTEP, WORDN, WORDN, 1, 1);

  // out[0] = p_8191
  hipMemcpyAsync(out, P + (long)NSTEP * WORDN, prow,
                 hipMemcpyDeviceToDevice, stream);
}

// Round 5
// 141284.875 us; speedup vs baseline: 1.5932x; 1.5932x over previous
//
#include <hip/hip_runtime.h>
#include <math.h>

#define WORDN 1024
#define HIDN  2048
#define ENCN  512
#define NODEN 8192
#define NSTEP (NODEN - 1)

#define CHAIN_WGS 32

// ---------------------------------------------------------------------------
// Persistent sequential-chain kernel: P[t+1] = tanh(W @ P[t] + addv_t)
// 32 WGs x 256 threads = 128 independent waves. Wave owns 8 rows; lane owns
// one (row, 128-col segment) pair; 128 weights/lane in VGPRs.
//
// Sync protocol (NO agent fences, NO RMWs, NO wbl2/inv):
//  producer: P-row stores = relaxed AGENT atomic stores (sc1, write-through
//            past the non-coherent per-XCD L2s to MALL);
//            workgroup-RELEASE fence (= compiler barrier + s_waitcnt vmcnt(0),
//            no cache ops) -- vmcnt ack of a write-through store means it
//            reached the coherence point;
//            lane0 publishes its flag with a relaxed AGENT store.
//  consumer: polls all 128 dense flags with ONE 8 B relaxed AGENT load per
//            lane; workgroup-ACQUIRE fence (compiler barrier only); then
//            PLAIN CACHED float4 loads of P[t] -- fresh by construction:
//            producers bypass L2, and no XCD's L2 can hold a line for row t
//            from before its flag was raised (rows are read only after their
//            flag; dispatch-boundary acquire invalidates cover reuse across
//            dispatches/replays -- validated by R1/R3/R4 passing).
// ---------------------------------------------------------------------------
__global__ __launch_bounds__(256, 1) void chain_kernel(
    const float* __restrict__ W, int ldw, int row_off,
    const float* __restrict__ addv, long addv_stride,
    float* __restrict__ P,
    unsigned int* __restrict__ flags)
{
  const int g    = blockIdx.x;       // 0..31
  const int tid  = threadIdx.x;      // 0..255
  const int lane = tid & 63;
  const int wave = tid >> 6;
  const int wgid = (g << 2) | wave;            // global wave id 0..127
  const int rloc = (wave << 3) | (lane >> 3);  // row within WG 0..31
  const int row  = (g << 5) | rloc;            // 0..1023
  const int seg  = lane & 7;                   // 128-col segment

  // One-time: this lane's 128 weights into VGPRs.
  float4 w[32];
  {
    const float* wr = W + (long)(row_off + row) * ldw + (seg << 7);
    #pragma unroll
    for (int i = 0; i < 32; ++i) w[i] = ((const float4*)wr)[i];
  }

  // Dense flag array: 128 x 4 B. Each lane polls one 8 B pair.
  const unsigned long long* fpair = (const unsigned long long*)flags + lane;

  for (int t = 0; t < NSTEP; ++t) {
    // Additive term: independent of the poll; issue early.
    float av = addv[(long)t * addv_stride + row];

    if (t > 0) {
      const unsigned int target = (unsigned int)t;
      while (true) {
        unsigned long long v =
            __hip_atomic_load(fpair, __ATOMIC_RELAXED, __HIP_MEMORY_SCOPE_AGENT);
        unsigned int a = (unsigned int)v;
        unsigned int b = (unsigned int)(v >> 32);
        if (__all(a >= target && b >= target)) break;
        __builtin_amdgcn_s_sleep(1);
      }
      // Compiler barrier only (workgroup scope => no L2 invalidate): keeps
      // the row loads below from being hoisted above the poll.
      __builtin_amdgcn_fence(__ATOMIC_ACQUIRE, "workgroup");
    }

    // Dot product: plain cached loads of this lane's 128-float segment.
    const float* pt = P + ((long)t << 10) + (seg << 7);
    float a0 = 0.f, a1 = 0.f, a2 = 0.f, a3 = 0.f;
    #pragma unroll
    for (int i = 0; i < 32; ++i) {
      float4 p4 = ((const float4*)pt)[i];
      a0 = fmaf(w[i].x, p4.x, a0);
      a1 = fmaf(w[i].y, p4.y, a1);
      a2 = fmaf(w[i].z, p4.z, a2);
      a3 = fmaf(w[i].w, p4.w, a3);
    }
    float acc = (a0 + a1) + (a2 + a3);
    // Reduce across the 8 lanes sharing a row.
    acc += __shfl_xor(acc, 1);
    acc += __shfl_xor(acc, 2);
    acc += __shfl_xor(acc, 4);
    if (seg == 0) {
      float outv = tanhf(acc + av);
      // Write-through to MALL (relaxed agent): no fence attached.
      __hip_atomic_store((unsigned int*)(P + ((long)(t + 1) << 10) + row),
                         __float_as_uint(outv),
                         __ATOMIC_RELAXED, __HIP_MEMORY_SCOPE_AGENT);
    }
    // Release = compiler barrier + vmcnt drain; sc1 stores are then at the
    // coherence point, so the relaxed flag store below is a correct publish.
    __builtin_amdgcn_fence(__ATOMIC_RELEASE, "workgroup");
    if (lane == 0) {
      __hip_atomic_store(flags + wgid, (unsigned int)(t + 1),
                         __ATOMIC_RELAXED, __HIP_MEMORY_SCOPE_AGENT);
    }
  }
}

// ---------------------------------------------------------------------------
// Wave-per-row matvec: y[r] = tanh(W[row_off+r,:] . x + b[b_off+r])
// ---------------------------------------------------------------------------
__global__ void matvec_tanh(const float* __restrict__ W, int ldw, int row_off,
                            const float* __restrict__ x, int K,
                            const float* __restrict__ b, int b_off,
                            float* __restrict__ y, int M)
{
  int gw   = (int)((blockIdx.x * blockDim.x + threadIdx.x) >> 6);
  int lane = threadIdx.x & 63;
  if (gw >= M) return;
  const float* wr = W + (long)(row_off + gw) * ldw;
  float acc = 0.f;
  for (int k = lane << 2; k < K; k += 256) {
    float4 wv = *(const float4*)(wr + k);
    float4 xv = *(const float4*)(x + k);
    acc = fmaf(wv.x, xv.x, acc);
    acc = fmaf(wv.y, xv.y, acc);
    acc = fmaf(wv.z, xv.z, acc);
    acc = fmaf(wv.w, xv.w, acc);
  }
  #pragma unroll
  for (int off = 1; off < 64; off <<= 1) acc += __shfl_xor(acc, off);
  if (lane == 0) y[gw] = tanhf(acc + b[b_off + gw]);
}

// z = eps * exp(0.5*va) + mu   (512 elements)
__global__ void z_kernel(const float* __restrict__ eps, const float* __restrict__ mu,
                         const float* __restrict__ va, float* __restrict__ z)
{
  int i = blockIdx.x * blockDim.x + threadIdx.x;
  z[i] = eps[i] * expf(0.5f * va[i]) + mu[i];
}

// ---------------------------------------------------------------------------
// fp32 tiled GEMM: C[crow(m), n] = (tanh?)( sum_k A[a_row0+m, k]*B[b_row0+n, k] + bias[n] )
// crow(m) = rev ? (M - m) : m.   BM=BN=128, BK=8, 256 threads, 8x8 microtile.
// ---------------------------------------------------------------------------
#define GBM 128
#define GBN 128
#define GBK 8

__global__ __launch_bounds__(256, 2) void gemm_bt(
    const float* __restrict__ A, long lda, long a_row0,
    const float* __restrict__ B, long ldb, long b_row0,
    const float* __restrict__ bias, long bias_off,
    float* __restrict__ C, long ldc,
    int M, int N, int K, int rev, int do_tanh)
{
  __shared__ float As[GBK][GBM + 4];
  __shared__ float Bs[GBK][GBN + 4];

  const int tid = threadIdx.x;
  const int bm = blockIdx.x, bn = blockIdx.y;
  const int tx = tid & 15;    // n dir
  const int ty = tid >> 4;    // m dir
  const int lr = tid >> 1;          // 0..127 staging row
  const int lc = (tid & 1) << 2;    // 0 or 4 staging col

  float acc[8][8];
  #pragma unroll
  for (int i = 0; i < 8; ++i)
    #pragma unroll
    for (int j = 0; j < 8; ++j) acc[i][j] = 0.f;

  for (int k0 = 0; k0 < K; k0 += GBK) {
    int am = bm * GBM + lr;
    float4 avv = make_float4(0.f, 0.f, 0.f, 0.f);
    if (am < M) avv = *(const float4*)(A + (a_row0 + am) * lda + k0 + lc);
    int bnr = bn * GBN + lr;
    float4 bvv = *(const float4*)(B + (b_row0 + bnr) * ldb + k0 + lc);

    As[lc + 0][lr] = avv.x; As[lc + 1][lr] = avv.y;
    As[lc + 2][lr] = avv.z; As[lc + 3][lr] = avv.w;
    Bs[lc + 0][lr] = bvv.x; Bs[lc + 1][lr] = bvv.y;
    Bs[lc + 2][lr] = bvv.z; Bs[lc + 3][lr] = bvv.w;
    __syncthreads();

    #pragma unroll
    for (int k = 0; k < GBK; ++k) {
      float4 a0 = *(const float4*)&As[k][ty << 2];
      float4 a1 = *(const float4*)&As[k][64 + (ty << 2)];
      float4 b0 = *(const float4*)&Bs[k][tx << 2];
      float4 b1 = *(const float4*)&Bs[k][64 + (tx << 2)];
      float aa[8] = {a0.x, a0.y, a0.z, a0.w, a1.x, a1.y, a1.z, a1.w};
      float bb[8] = {b0.x, b0.y, b0.z, b0.w, b1.x, b1.y, b1.z, b1.w};
      #pragma unroll
      for (int i = 0; i < 8; ++i)
        #pragma unroll
        for (int j = 0; j < 8; ++j)
          acc[i][j] = fmaf(aa[i], bb[j], acc[i][j]);
    }
    __syncthreads();
  }

  // Epilogue
  #pragma unroll
  for (int hm = 0; hm < 2; ++hm) {
    #pragma unroll
    for (int i = 0; i < 4; ++i) {
      int m = bm * GBM + hm * 64 + (ty << 2) + i;
      if (m >= M) continue;
      long crow = rev ? (long)(M - m) : (long)m;
      #pragma unroll
      for (int hn = 0; hn < 2; ++hn) {
        int n0 = bn * GBN + hn * 64 + (tx << 2);
        float4 v;
        v.x = acc[hm * 4 + i][hn * 4 + 0] + bias[bias_off + n0 + 0];
        v.y = acc[hm * 4 + i][hn * 4 + 1] + bias[bias_off + n0 + 1];
        v.z = acc[hm * 4 + i][hn * 4 + 2] + bias[bias_off + n0 + 2];
        v.w = acc[hm * 4 + i][hn * 4 + 3] + bias[bias_off + n0 + 3];
        if (do_tanh) {
          v.x = tanhf(v.x); v.y = tanhf(v.y); v.z = tanhf(v.z); v.w = tanhf(v.w);
        }
        *(float4*)(C + crow * ldc + n0) = v;
      }
    }
  }
}

// ---------------------------------------------------------------------------
extern "C" void kernel_launch(void* const* d_in, const int* in_sizes, int n_in,
                              void* d_out, int out_size, void* d_ws, size_t ws_size,
                              hipStream_t stream)
{
  const float* sent    = (const float*)d_in[0];
  const float* eps     = (const float*)d_in[1];
  const float* WeC2P_w = (const float*)d_in[2];
  const float* WeC2P_b = (const float*)d_in[3];
  const float* WeP2H_w = (const float*)d_in[4];
  const float* WeP2H_b = (const float*)d_in[5];
  const float* WeH2M_w = (const float*)d_in[6];
  const float* WeH2M_b = (const float*)d_in[7];
  const float* WeH2D_w = (const float*)d_in[8];
  const float* WeH2D_b = (const float*)d_in[9];
  const float* WdE2H_w = (const float*)d_in[10];
  const float* WdE2H_b = (const float*)d_in[11];
  const float* WdH2P_w = (const float*)d_in[12];
  const float* WdH2P_b = (const float*)d_in[13];
  const float* WdP2C_w = (const float*)d_in[14];
  const float* WdP2C_b = (const float*)d_in[15];
  float* out = (float*)d_out;

  char* ws = (char*)d_ws;
  unsigned int* flags0 = (unsigned int*)ws;                    // 128 x 4 B dense
  unsigned int* flags1 = (unsigned int*)(ws + 4096);           // 128 x 4 B dense
  float* hid  = (float*)(ws + 16384);                          // 2048
  float* mu   = hid + HIDN;                                    // 512
  float* va   = mu + ENCN;                                     // 512
  float* z    = va + ENCN;                                     // 512
  float* hdec = z + ENCN;                                      // 2048
  float* P    = (float*)(ws + 65536);                          // 8192 x 1024 fp32 (32 MB)

  const size_t prow = (size_t)WORDN * sizeof(float);

  hipMemsetAsync(ws, 0, 8192, stream);   // both flag arrays
  // P[0] = sent[0]  (encode seed; dispatch boundary makes it visible)
  hipMemcpyAsync(P, sent, prow, hipMemcpyDeviceToDevice, stream);

  dim3 gg((NSTEP + GBM - 1) / GBM, WORDN / GBN);  // (64, 8)

  // U[t] = Wx @ sent[t+1] + b_enc   -> stored in d_out (scratch; overwritten later)
  gemm_bt<<<gg, 256, 0, stream>>>(sent, WORDN, 1,
                                  WeC2P_w + WORDN, 2 * WORDN, 0,
                                  WeC2P_b, 0,
                                  out, WORDN,
                                  NSTEP, WORDN, WORDN, 0, 0);

  // Encode chain: P[t+1] = tanh(Wp @ P[t] + U[t]),  t = 0..8190
  chain_kernel<<<CHAIN_WGS, 256, 0, stream>>>(WeC2P_w, 2 * WORDN, 0,
                                              out, WORDN, P, flags0);

  // hid = tanh(WeP2H @ P[8191] + b)
  matvec_tanh<<<(HIDN * 64) / 256, 256, 0, stream>>>(WeP2H_w, WORDN, 0,
                                                     P + (long)NSTEP * WORDN, WORDN,
                                                     WeP2H_b, 0, hid, HIDN);
  // mu, va
  matvec_tanh<<<(ENCN * 64) / 256, 256, 0, stream>>>(WeH2M_w, HIDN, 0, hid, HIDN,
                                                     WeH2M_b, 0, mu, ENCN);
  matvec_tanh<<<(ENCN * 64) / 256, 256, 0, stream>>>(WeH2D_w, HIDN, 0, hid, HIDN,
                                                     WeH2D_b, 0, va, ENCN);
  // z = eps * exp(0.5 va) + mu
  z_kernel<<<ENCN / 256, 256, 0, stream>>>(eps, mu, va, z);
  // hdec = tanh(WdE2H @ z + b)
  matvec_tanh<<<(HIDN * 64) / 256, 256, 0, stream>>>(WdE2H_w, ENCN, 0, z, ENCN,
                                                     WdE2H_b, 0, hdec, HIDN);
  // parent_d = tanh(WdH2P @ hdec + b)  -> P[0]  (decode seed)
  matvec_tanh<<<(WORDN * 64) / 256, 256, 0, stream>>>(WdH2P_w, HIDN, 0, hdec, HIDN,
                                                      WdH2P_b, 0, P, WORDN);

  // Decode chain: P[t+1] = tanh(Wbot @ P[t] + b_bot), t = 0..8190
  chain_kernel<<<CHAIN_WGS, 256, 0, stream>>>(WdP2C_w, WORDN, WORDN,
                                              WdP2C_b + WORDN, 0, P, flags1);

  // out[8191 - i] = tanh(Wtop @ P[i] + b_top), i = 0..8190
  gemm_bt<<<gg, 256, 0, stream>>>(P, WORDN, 0,
                                  WdP2C_w, WORDN, 0,
                                  WdP2C_b, 0,
                                  out, WORDN,
                                  NSTEP, WORDN, WORDN, 1, 1);

  // out[0] = p_8191
  hipMemcpyAsync(out, P + (long)NSTEP * WORDN, prow,
                 hipMemcpyDeviceToDevice, stream);
}

// Round 6
// 92425.397 us; speedup vs baseline: 2.4354x; 1.5286x over previous
//
#include <hip/hip_runtime.h>
#include <math.h>

#define WORDN 1024
#define HIDN  2048
#define ENCN  512
#define NODEN 8192
#define NSTEP (NODEN - 1)

#define CHAIN_WGS 32
#define CTR_STRIDE 64   // uints -> one counter per 256 B

// ---------------------------------------------------------------------------
// Persistent sequential-chain kernel: P[t+1] = tanh(W @ P[t] + addv_t)
// 32 WGs x 256 threads. Wave owns 8 rows; lane owns one (row, 128-col seg).
// 128 weights/lane in VGPRs.
//
// Protocol = R1's (best measured: plain cached stores + release-RMW publish)
// with the single hot counter split 8 ways:
//  producer: plain stores of row t+1 -> local L2 (dirty); __syncthreads
//            (drains all 4 waves' stores, vmcnt(0) before s_barrier); tid0
//            does ONE agent-RELEASE atomicAdd on counter[g&7] -- the release
//            emits buffer_wbl2 (publishes the WG's dirty lines to MALL) then
//            the add. 4 adds per line x 8 lines in parallel vs R1's 32 on 1.
//  consumer: wave0 spins with one relaxed agent load (lanes read ctr[lane&7],
//            8 distinct lines in parallel) until all reach 4*t; workgroup
//            acquire fence (compiler order only -- no cache ops needed: a
//            consumer's L2/L1 never held a P-row line before its counter
//            tripped, and dispatch-boundary invalidates cover replays);
//            __syncthreads releases the other 3 waves; plain cached float4
//            loads of P[t].
// ---------------------------------------------------------------------------
__global__ __launch_bounds__(256, 1) void chain_kernel(
    const float* __restrict__ W, int ldw, int row_off,
    const float* __restrict__ addv, long addv_stride,
    float* __restrict__ P,
    unsigned int* __restrict__ ctr)
{
  const int g    = blockIdx.x;       // 0..31
  const int tid  = threadIdx.x;      // 0..255
  const int lane = tid & 63;
  const int wave = tid >> 6;
  const int rloc = (wave << 3) | (lane >> 3);  // row within WG 0..31
  const int row  = (g << 5) | rloc;            // 0..1023
  const int seg  = lane & 7;                   // 128-col segment

  // One-time: this lane's 128 weights into VGPRs.
  float4 w[32];
  {
    const float* wr = W + (long)(row_off + row) * ldw + (seg << 7);
    #pragma unroll
    for (int i = 0; i < 32; ++i) w[i] = ((const float4*)wr)[i];
  }

  const unsigned int* myctr = ctr + ((unsigned)(lane & 7) * CTR_STRIDE);
  unsigned int* pubctr = ctr + ((unsigned)(g & 7) * CTR_STRIDE);

  for (int t = 0; t < NSTEP; ++t) {
    // Wait for P[t] (all 32 WGs published step t-1). t=0 seed comes from a
    // prior dispatch (coherent via dispatch boundary).
    if (t > 0) {
      if (wave == 0) {
        const unsigned int target = 4u * (unsigned int)t;
        while (true) {
          unsigned int c = __hip_atomic_load(myctr, __ATOMIC_RELAXED,
                                             __HIP_MEMORY_SCOPE_AGENT);
          if (__all(c >= target)) break;
          __builtin_amdgcn_s_sleep(1);
        }
        // Compiler-order only; no cache maintenance.
        __builtin_amdgcn_fence(__ATOMIC_ACQUIRE, "workgroup");
      }
      __syncthreads();
    }

    // Additive term (plain cached; the WG's 32 rows = one 128 B line).
    float av = addv[(long)t * addv_stride + row];

    // Dot product: plain cached loads of this lane's 128-float segment.
    const float* pt = P + ((long)t << 10) + (seg << 7);
    float a0 = 0.f, a1 = 0.f, a2 = 0.f, a3 = 0.f;
    #pragma unroll
    for (int i = 0; i < 32; ++i) {
      float4 p4 = ((const float4*)pt)[i];
      a0 = fmaf(w[i].x, p4.x, a0);
      a1 = fmaf(w[i].y, p4.y, a1);
      a2 = fmaf(w[i].z, p4.z, a2);
      a3 = fmaf(w[i].w, p4.w, a3);
    }
    float acc = (a0 + a1) + (a2 + a3);
    // Reduce across the 8 lanes sharing a row.
    acc += __shfl_xor(acc, 1);
    acc += __shfl_xor(acc, 2);
    acc += __shfl_xor(acc, 4);
    if (seg == 0) {
      // Plain store -> local L2 (published by the release-RMW's wbl2 below).
      P[((long)(t + 1) << 10) + row] = tanhf(acc + av);
    }

    // All 4 waves' stores drained to L2 (vmcnt(0) precedes s_barrier).
    __syncthreads();
    if (tid == 0) {
      __hip_atomic_fetch_add(pubctr, 1u, __ATOMIC_RELEASE,
                             __HIP_MEMORY_SCOPE_AGENT);
    }
  }
}

// ---------------------------------------------------------------------------
// Wave-per-row matvec: y[r] = tanh(W[row_off+r,:] . x + b[b_off+r])
// ---------------------------------------------------------------------------
__global__ void matvec_tanh(const float* __restrict__ W, int ldw, int row_off,
                            const float* __restrict__ x, int K,
                            const float* __restrict__ b, int b_off,
                            float* __restrict__ y, int M)
{
  int gw   = (int)((blockIdx.x * blockDim.x + threadIdx.x) >> 6);
  int lane = threadIdx.x & 63;
  if (gw >= M) return;
  const float* wr = W + (long)(row_off + gw) * ldw;
  float acc = 0.f;
  for (int k = lane << 2; k < K; k += 256) {
    float4 wv = *(const float4*)(wr + k);
    float4 xv = *(const float4*)(x + k);
    acc = fmaf(wv.x, xv.x, acc);
    acc = fmaf(wv.y, xv.y, acc);
    acc = fmaf(wv.z, xv.z, acc);
    acc = fmaf(wv.w, xv.w, acc);
  }
  #pragma unroll
  for (int off = 1; off < 64; off <<= 1) acc += __shfl_xor(acc, off);
  if (lane == 0) y[gw] = tanhf(acc + b[b_off + gw]);
}

// z = eps * exp(0.5*va) + mu   (512 elements)
__global__ void z_kernel(const float* __restrict__ eps, const float* __restrict__ mu,
                         const float* __restrict__ va, float* __restrict__ z)
{
  int i = blockIdx.x * blockDim.x + threadIdx.x;
  z[i] = eps[i] * expf(0.5f * va[i]) + mu[i];
}

// ---------------------------------------------------------------------------
// fp32 tiled GEMM: C[crow(m), n] = (tanh?)( sum_k A[a_row0+m, k]*B[b_row0+n, k] + bias[n] )
// crow(m) = rev ? (M - m) : m.   BM=BN=128, BK=8, 256 threads, 8x8 microtile.
// ---------------------------------------------------------------------------
#define GBM 128
#define GBN 128
#define GBK 8

__global__ __launch_bounds__(256, 2) void gemm_bt(
    const float* __restrict__ A, long lda, long a_row0,
    const float* __restrict__ B, long ldb, long b_row0,
    const float* __restrict__ bias, long bias_off,
    float* __restrict__ C, long ldc,
    int M, int N, int K, int rev, int do_tanh)
{
  __shared__ float As[GBK][GBM + 4];
  __shared__ float Bs[GBK][GBN + 4];

  const int tid = threadIdx.x;
  const int bm = blockIdx.x, bn = blockIdx.y;
  const int tx = tid & 15;    // n dir
  const int ty = tid >> 4;    // m dir
  const int lr = tid >> 1;          // 0..127 staging row
  const int lc = (tid & 1) << 2;    // 0 or 4 staging col

  float acc[8][8];
  #pragma unroll
  for (int i = 0; i < 8; ++i)
    #pragma unroll
    for (int j = 0; j < 8; ++j) acc[i][j] = 0.f;

  for (int k0 = 0; k0 < K; k0 += GBK) {
    int am = bm * GBM + lr;
    float4 avv = make_float4(0.f, 0.f, 0.f, 0.f);
    if (am < M) avv = *(const float4*)(A + (a_row0 + am) * lda + k0 + lc);
    int bnr = bn * GBN + lr;
    float4 bvv = *(const float4*)(B + (b_row0 + bnr) * ldb + k0 + lc);

    As[lc + 0][lr] = avv.x; As[lc + 1][lr] = avv.y;
    As[lc + 2][lr] = avv.z; As[lc + 3][lr] = avv.w;
    Bs[lc + 0][lr] = bvv.x; Bs[lc + 1][lr] = bvv.y;
    Bs[lc + 2][lr] = bvv.z; Bs[lc + 3][lr] = bvv.w;
    __syncthreads();

    #pragma unroll
    for (int k = 0; k < GBK; ++k) {
      float4 a0 = *(const float4*)&As[k][ty << 2];
      float4 a1 = *(const float4*)&As[k][64 + (ty << 2)];
      float4 b0 = *(const float4*)&Bs[k][tx << 2];
      float4 b1 = *(const float4*)&Bs[k][64 + (tx << 2)];
      float aa[8] = {a0.x, a0.y, a0.z, a0.w, a1.x, a1.y, a1.z, a1.w};
      float bb[8] = {b0.x, b0.y, b0.z, b0.w, b1.x, b1.y, b1.z, b1.w};
      #pragma unroll
      for (int i = 0; i < 8; ++i)
        #pragma unroll
        for (int j = 0; j < 8; ++j)
          acc[i][j] = fmaf(aa[i], bb[j], acc[i][j]);
    }
    __syncthreads();
  }

  // Epilogue
  #pragma unroll
  for (int hm = 0; hm < 2; ++hm) {
    #pragma unroll
    for (int i = 0; i < 4; ++i) {
      int m = bm * GBM + hm * 64 + (ty << 2) + i;
      if (m >= M) continue;
      long crow = rev ? (long)(M - m) : (long)m;
      #pragma unroll
      for (int hn = 0; hn < 2; ++hn) {
        int n0 = bn * GBN + hn * 64 + (tx << 2);
        float4 v;
        v.x = acc[hm * 4 + i][hn * 4 + 0] + bias[bias_off + n0 + 0];
        v.y = acc[hm * 4 + i][hn * 4 + 1] + bias[bias_off + n0 + 1];
        v.z = acc[hm * 4 + i][hn * 4 + 2] + bias[bias_off + n0 + 2];
        v.w = acc[hm * 4 + i][hn * 4 + 3] + bias[bias_off + n0 + 3];
        if (do_tanh) {
          v.x = tanhf(v.x); v.y = tanhf(v.y); v.z = tanhf(v.z); v.w = tanhf(v.w);
        }
        *(float4*)(C + crow * ldc + n0) = v;
      }
    }
  }
}

// ---------------------------------------------------------------------------
extern "C" void kernel_launch(void* const* d_in, const int* in_sizes, int n_in,
                              void* d_out, int out_size, void* d_ws, size_t ws_size,
                              hipStream_t stream)
{
  const float* sent    = (const float*)d_in[0];
  const float* eps     = (const float*)d_in[1];
  const float* WeC2P_w = (const float*)d_in[2];
  const float* WeC2P_b = (const float*)d_in[3];
  const float* WeP2H_w = (const float*)d_in[4];
  const float* WeP2H_b = (const float*)d_in[5];
  const float* WeH2M_w = (const float*)d_in[6];
  const float* WeH2M_b = (const float*)d_in[7];
  const float* WeH2D_w = (const float*)d_in[8];
  const float* WeH2D_b = (const float*)d_in[9];
  const float* WdE2H_w = (const float*)d_in[10];
  const float* WdE2H_b = (const float*)d_in[11];
  const float* WdH2P_w = (const float*)d_in[12];
  const float* WdH2P_b = (const float*)d_in[13];
  const float* WdP2C_w = (const float*)d_in[14];
  const float* WdP2C_b = (const float*)d_in[15];
  float* out = (float*)d_out;

  char* ws = (char*)d_ws;
  unsigned int* ctr0 = (unsigned int*)ws;                      // 8 x 256 B
  unsigned int* ctr1 = (unsigned int*)(ws + 4096);             // 8 x 256 B
  float* hid  = (float*)(ws + 16384);                          // 2048
  float* mu   = hid + HIDN;                                    // 512
  float* va   = mu + ENCN;                                     // 512
  float* z    = va + ENCN;                                     // 512
  float* hdec = z + ENCN;                                      // 2048
  float* P    = (float*)(ws + 65536);                          // 8192 x 1024 fp32 (32 MB)

  const size_t prow = (size_t)WORDN * sizeof(float);

  hipMemsetAsync(ws, 0, 8192, stream);   // both counter arrays
  // P[0] = sent[0]  (encode seed; dispatch boundary makes it visible)
  hipMemcpyAsync(P, sent, prow, hipMemcpyDeviceToDevice, stream);

  dim3 gg((NSTEP + GBM - 1) / GBM, WORDN / GBN);  // (64, 8)

  // U[t] = Wx @ sent[t+1] + b_enc   -> stored in d_out (scratch; overwritten later)
  gemm_bt<<<gg, 256, 0, stream>>>(sent, WORDN, 1,
                                  WeC2P_w + WORDN, 2 * WORDN, 0,
                                  WeC2P_b, 0,
                                  out, WORDN,
                                  NSTEP, WORDN, WORDN, 0, 0);

  // Encode chain: P[t+1] = tanh(Wp @ P[t] + U[t]),  t = 0..8190
  chain_kernel<<<CHAIN_WGS, 256, 0, stream>>>(WeC2P_w, 2 * WORDN, 0,
                                              out, WORDN, P, ctr0);

  // hid = tanh(WeP2H @ P[8191] + b)
  matvec_tanh<<<(HIDN * 64) / 256, 256, 0, stream>>>(WeP2H_w, WORDN, 0,
                                                     P + (long)NSTEP * WORDN, WORDN,
                                                     WeP2H_b, 0, hid, HIDN);
  // mu, va
  matvec_tanh<<<(ENCN * 64) / 256, 256, 0, stream>>>(WeH2M_w, HIDN, 0, hid, HIDN,
                                                     WeH2M_b, 0, mu, ENCN);
  matvec_tanh<<<(ENCN * 64) / 256, 256, 0, stream>>>(WeH2D_w, HIDN, 0, hid, HIDN,
                                                     WeH2D_b, 0, va, ENCN);
  // z = eps * exp(0.5 va) + mu
  z_kernel<<<ENCN / 256, 256, 0, stream>>>(eps, mu, va, z);
  // hdec = tanh(WdE2H @ z + b)
  matvec_tanh<<<(HIDN * 64) / 256, 256, 0, stream>>>(WdE2H_w, ENCN, 0, z, ENCN,
                                                     WdE2H_b, 0, hdec, HIDN);
  // parent_d = tanh(WdH2P @ hdec + b)  -> P[0]  (decode seed)
  matvec_tanh<<<(WORDN * 64) / 256, 256, 0, stream>>>(WdH2P_w, HIDN, 0, hdec, HIDN,
                                                      WdH2P_b, 0, P, WORDN);

  // Decode chain: P[t+1] = tanh(Wbot @ P[t] + b_bot), t = 0..8190
  chain_kernel<<<CHAIN_WGS, 256, 0, stream>>>(WdP2C_w, WORDN, WORDN,
                                              WdP2C_b + WORDN, 0, P, ctr1);

  // out[8191 - i] = tanh(Wtop @ P[i] + b_top), i = 0..8190
  gemm_bt<<<gg, 256, 0, stream>>>(P, WORDN, 0,
                                  WdP2C_w, WORDN, 0,
                                  WdP2C_b, 0,
                                  out, WORDN,
                                  NSTEP, WORDN, WORDN, 1, 1);

  // out[0] = p_8191
  hipMemcpyAsync(out, P + (long)NSTEP * WORDN, prow,
                 hipMemcpyDeviceToDevice, stream);
}